// Round 1
// baseline (3519.732 us; speedup 1.0000x reference)
//
#include <hip/hip_runtime.h>
#include <hip/hip_bf16.h>
#include <math.h>

#define BN 2
#define NPTS 4096
#define DIM 64
#define HID 256
#define KNB 16

// ---------------------------------------------------------------------------
// Kernel 1: qkv = x @ w_qkv + b_qkv.   [8192,64] @ [64,192]
// grid 256 blocks x 256 thr; each block: 32 rows.
// ---------------------------------------------------------------------------
__global__ __launch_bounds__(256) void qkv_kernel(
    const float* __restrict__ x, const float* __restrict__ w,
    const float* __restrict__ b, float* __restrict__ qkv) {
  __shared__ float sw[64 * 192];   // 48 KB
  __shared__ float sx[32 * 64];    // 8 KB
  int tid = threadIdx.x;
  int row0 = blockIdx.x * 32;
  for (int o = tid; o < 64 * 192; o += 256) sw[o] = w[o];
  for (int o = tid; o < 32 * 64; o += 256) sx[o] = x[(size_t)row0 * 64 + o];
  __syncthreads();
  for (int o = tid; o < 32 * 192; o += 256) {
    int r = o / 192, c = o % 192;
    float acc = b[c];
    const float* xr = &sx[r * 64];
#pragma unroll
    for (int d = 0; d < 64; ++d) acc = fmaf(xr[d], sw[d * 192 + c], acc);
    qkv[(size_t)(row0 + r) * 192 + c] = acc;
  }
}

// ---------------------------------------------------------------------------
// Kernel 2: KNN top-16 smallest distances (tie-break: smaller index).
// grid 256 blocks (2 batches x 128), block 256 thr = 32 points x 8 subranges.
// ---------------------------------------------------------------------------
__global__ __launch_bounds__(256) void knn_kernel(
    const float* __restrict__ pos, int* __restrict__ knn) {
  __shared__ float sd[256 * 16];   // 16 KB
  __shared__ int si[256 * 16];     // 16 KB
  __shared__ int scur[32][8];      // merge cursors
  int blk = blockIdx.x;
  int b = blk >> 7;
  int i0 = (blk & 127) * 32;
  int tid = threadIdx.x;
  int p = tid & 31;      // point in group
  int sub = tid >> 5;    // candidate subrange 0..7
  int i = i0 + p;
  const float* posb = pos + (size_t)b * NPTS * 3;
  float pix = posb[i * 3 + 0], piy = posb[i * 3 + 1], piz = posb[i * 3 + 2];

  float bd[16];
  int bidx[16];
#pragma unroll
  for (int s = 0; s < 16; ++s) { bd[s] = 1e30f; bidx[s] = 0x7fffffff; }

  int j0 = sub * (NPTS / 8);
  for (int jj = 0; jj < NPTS / 8; ++jj) {
    int j = j0 + jj;
    float dx = pix - posb[j * 3 + 0];
    float dy = piy - posb[j * 3 + 1];
    float dz = piz - posb[j * 3 + 2];
    float dist = sqrtf(dx * dx + dy * dy + dz * dz);
    if (dist < bd[15] || (dist == bd[15] && j < bidx[15])) {
      bd[15] = dist; bidx[15] = j;
#pragma unroll
      for (int s = 15; s > 0; --s) {
        bool sw = (bd[s] < bd[s - 1]) ||
                  (bd[s] == bd[s - 1] && bidx[s] < bidx[s - 1]);
        float td = sw ? bd[s - 1] : bd[s];
        float tu = sw ? bd[s] : bd[s - 1];
        int ti = sw ? bidx[s - 1] : bidx[s];
        int tj = sw ? bidx[s] : bidx[s - 1];
        bd[s] = td; bd[s - 1] = tu; bidx[s] = ti; bidx[s - 1] = tj;
      }
    }
  }
  int base = (p * 8 + sub) * 16;
#pragma unroll
  for (int s = 0; s < 16; ++s) { sd[base + s] = bd[s]; si[base + s] = bidx[s]; }
  __syncthreads();

  if (tid < 32) {
    int pp = tid;
#pragma unroll
    for (int s = 0; s < 8; ++s) scur[pp][s] = 0;
    size_t ob = ((size_t)(b * NPTS) + i0 + pp) * KNB;
    for (int m = 0; m < KNB; ++m) {
      float bestd = 1e31f;
      int besti = 0x7fffffff, bests = 0;
#pragma unroll
      for (int s = 0; s < 8; ++s) {
        int cs = scur[pp][s];
        if (cs < 16) {
          float d = sd[(pp * 8 + s) * 16 + cs];
          int id = si[(pp * 8 + s) * 16 + cs];
          if (d < bestd || (d == bestd && id < besti)) {
            bestd = d; besti = id; bests = s;
          }
        }
      }
      knn[ob + m] = besti;
      scur[pp][bests]++;
    }
  }
}

// ---------------------------------------------------------------------------
// Kernel 3: per-point attention. One block (256 thr) per (b,i).
//   e   = relu(rel @ w_p1 + b_p1)                [16,64]
//   h   = q - k_nb + e @ w_p2 + b_p2             [16,64]
//   t   = relu(h @ w_a1 + b_a1)                  [16,256]
//   sc  = t @ w_a2 + b_a2                        [16,64]
//   agg = sum_k softmax_k(sc) * v_nb             [64]
// ---------------------------------------------------------------------------
__global__ __launch_bounds__(256) void attn_kernel(
    const float* __restrict__ qkv, const float* __restrict__ pos,
    const int* __restrict__ knn,
    const float* __restrict__ w_p1, const float* __restrict__ b_p1,
    const float* __restrict__ w_p2, const float* __restrict__ b_p2,
    const float* __restrict__ w_a1, const float* __restrict__ b_a1,
    const float* __restrict__ w_a2, const float* __restrict__ b_a2,
    float* __restrict__ aggout) {
  __shared__ int sidx[16];
  __shared__ float sq[64];
  __shared__ float spi[3];
  __shared__ float se[16][64];          // 4 KB
  __shared__ float sh[16][64];          // 4 KB
  __shared__ float sv[16][64];          // 4 KB
  __shared__ float st[16][256];         // 16 KB
  __shared__ float ssc[16][64];         // 4 KB
  __shared__ float spart[4][16][64];    // 16 KB

  int bi = blockIdx.x;            // b*4096 + i
  int b = bi >> 12;
  int tid = threadIdx.x;
  if (tid < 16) sidx[tid] = knn[(size_t)bi * KNB + tid];
  if (tid < 64) sq[tid] = qkv[(size_t)bi * 192 + tid];
  if (tid < 3) spi[tid] = pos[(size_t)bi * 3 + tid];
  __syncthreads();

  // e[k][p]
  for (int o = tid; o < 16 * 64; o += 256) {
    int k = o >> 6, p = o & 63;
    int jb = (b << 12) | sidx[k];
    float rx = spi[0] - pos[(size_t)jb * 3 + 0];
    float ry = spi[1] - pos[(size_t)jb * 3 + 1];
    float rz = spi[2] - pos[(size_t)jb * 3 + 2];
    float acc = b_p1[p];
    acc = fmaf(rx, w_p1[p], acc);
    acc = fmaf(ry, w_p1[64 + p], acc);
    acc = fmaf(rz, w_p1[128 + p], acc);
    se[k][p] = fmaxf(acc, 0.f);
  }
  __syncthreads();

  // h[k][d] and v_nb[k][d]
  for (int o = tid; o < 16 * 64; o += 256) {
    int k = o >> 6, d = o & 63;
    int jb = (b << 12) | sidx[k];
    float acc = b_p2[d];
#pragma unroll
    for (int p = 0; p < 64; ++p) acc = fmaf(se[k][p], w_p2[p * 64 + d], acc);
    float kv = qkv[(size_t)jb * 192 + 64 + d];
    sh[k][d] = sq[d] - kv + acc;
    sv[k][d] = qkv[(size_t)jb * 192 + 128 + d];
  }
  __syncthreads();

  // t[k][j]: thread owns column j = tid, 16 k-accumulators in regs.
  {
    int j = tid;
    float acc[16];
#pragma unroll
    for (int k = 0; k < 16; ++k) acc[k] = b_a1[j];
    for (int d = 0; d < 64; ++d) {
      float wv = w_a1[d * 256 + j];
#pragma unroll
      for (int k = 0; k < 16; ++k) acc[k] = fmaf(sh[k][d], wv, acc[k]);
    }
#pragma unroll
    for (int k = 0; k < 16; ++k) st[k][j] = fmaxf(acc[k], 0.f);
  }
  __syncthreads();

  // sc[k][d]: wave w handles j in [w*64,(w+1)*64); partials reduced in LDS.
  {
    int lane = tid & 63, w = tid >> 6;
    float acc[16];
#pragma unroll
    for (int k = 0; k < 16; ++k) acc[k] = 0.f;
    for (int jj = 0; jj < 64; ++jj) {
      int j = w * 64 + jj;
      float wv = w_a2[j * 64 + lane];
#pragma unroll
      for (int k = 0; k < 16; ++k) acc[k] = fmaf(st[k][j], wv, acc[k]);
    }
#pragma unroll
    for (int k = 0; k < 16; ++k) spart[w][k][lane] = acc[k];
  }
  __syncthreads();
  for (int o = tid; o < 16 * 64; o += 256) {
    int k = o >> 6, d = o & 63;
    ssc[k][d] = b_a2[d] + spart[0][k][d] + spart[1][k][d] + spart[2][k][d] +
                spart[3][k][d];
  }
  __syncthreads();

  // softmax over k (per channel d) + weighted sum of v
  if (tid < 64) {
    int d = tid;
    float m = -1e30f;
#pragma unroll
    for (int k = 0; k < 16; ++k) m = fmaxf(m, ssc[k][d]);
    float s = 0.f, a = 0.f;
#pragma unroll
    for (int k = 0; k < 16; ++k) {
      float e = expf(ssc[k][d] - m);
      s += e;
      a = fmaf(e, sv[k][d], a);
    }
    aggout[(size_t)bi * 64 + d] = a / s;
  }
}

// ---------------------------------------------------------------------------
// Kernel 4: y = agg @ w_fc + b_fc; accumulate per-channel sum/sumsq.
// grid 128 blocks x 256 thr; 64 rows per block.
// ---------------------------------------------------------------------------
__global__ __launch_bounds__(256) void fc_kernel(
    const float* __restrict__ agg, const float* __restrict__ w_fc,
    const float* __restrict__ b_fc, float* __restrict__ y,
    float* __restrict__ stats) {
  __shared__ float sw[64 * 64];    // 16 KB
  __shared__ float sa[64 * 64];    // 16 KB
  __shared__ float red[4][64];
  __shared__ float red2[4][64];
  int tid = threadIdx.x;
  int r0 = blockIdx.x * 64;
  for (int o = tid; o < 4096; o += 256) sw[o] = w_fc[o];
  for (int o = tid; o < 4096; o += 256) sa[o] = agg[(size_t)r0 * 64 + o];
  __syncthreads();
  int c = tid & 63, g = tid >> 6;
  float psum = 0.f, psq = 0.f;
  for (int rr = g; rr < 64; rr += 4) {
    float acc = b_fc[c];
#pragma unroll
    for (int d = 0; d < 64; ++d) acc = fmaf(sa[rr * 64 + d], sw[d * 64 + c], acc);
    y[(size_t)(r0 + rr) * 64 + c] = acc;
    psum += acc;
    psq = fmaf(acc, acc, psq);
  }
  red[g][c] = psum;
  red2[g][c] = psq;
  __syncthreads();
  if (tid < 64) {
    float s = red[0][tid] + red[1][tid] + red[2][tid] + red[3][tid];
    float s2 = red2[0][tid] + red2[1][tid] + red2[2][tid] + red2[3][tid];
    atomicAdd(&stats[tid], s);
    atomicAdd(&stats[64 + tid], s2);
  }
}

// ---------------------------------------------------------------------------
// Kernel 5: BN (batch stats) + relu + residual.
// ---------------------------------------------------------------------------
__global__ __launch_bounds__(256) void bn_kernel(
    const float* __restrict__ y, const float* __restrict__ x,
    const float* __restrict__ stats, const float* __restrict__ gamma,
    const float* __restrict__ beta, float* __restrict__ out) {
  size_t o = (size_t)blockIdx.x * 256 + threadIdx.x;
  int c = (int)(o & 63);
  const float inv_n = 1.f / 8192.f;
  float mean = stats[c] * inv_n;
  float var = stats[64 + c] * inv_n - mean * mean;
  float inv = rsqrtf(var + 1e-5f);
  float v = (y[o] - mean) * inv * gamma[c] + beta[c];
  out[o] = fmaxf(v, 0.f) + x[o];
}

// ---------------------------------------------------------------------------
extern "C" void kernel_launch(void* const* d_in, const int* in_sizes, int n_in,
                              void* d_out, int out_size, void* d_ws,
                              size_t ws_size, hipStream_t stream) {
  const float* x = (const float*)d_in[0];
  const float* pos = (const float*)d_in[1];
  const float* w_qkv = (const float*)d_in[2];
  const float* b_qkv = (const float*)d_in[3];
  const float* w_p1 = (const float*)d_in[4];
  const float* b_p1 = (const float*)d_in[5];
  const float* w_p2 = (const float*)d_in[6];
  const float* b_p2 = (const float*)d_in[7];
  const float* w_a1 = (const float*)d_in[8];
  const float* b_a1 = (const float*)d_in[9];
  const float* w_a2 = (const float*)d_in[10];
  const float* b_a2 = (const float*)d_in[11];
  const float* w_fc = (const float*)d_in[12];
  const float* b_fc = (const float*)d_in[13];
  const float* gamma = (const float*)d_in[14];
  const float* beta = (const float*)d_in[15];

  char* ws = (char*)d_ws;
  float* qkv = (float*)(ws + 0);              // 8192*192*4 = 6291456
  int* knn = (int*)(ws + 6291456);            // 8192*16*4  = 524288
  float* agg = (float*)(ws + 6815744);        // 8192*64*4  = 2097152
  float* y = (float*)(ws + 8912896);          // 8192*64*4  = 2097152
  float* stats = (float*)(ws + 11010048);     // 128*4      = 512

  hipMemsetAsync(stats, 0, 512, stream);
  hipLaunchKernelGGL(qkv_kernel, dim3(256), dim3(256), 0, stream, x, w_qkv,
                     b_qkv, qkv);
  hipLaunchKernelGGL(knn_kernel, dim3(256), dim3(256), 0, stream, pos, knn);
  hipLaunchKernelGGL(attn_kernel, dim3(8192), dim3(256), 0, stream, qkv, pos,
                     knn, w_p1, b_p1, w_p2, b_p2, w_a1, b_a1, w_a2, b_a2, agg);
  hipLaunchKernelGGL(fc_kernel, dim3(128), dim3(256), 0, stream, agg, w_fc,
                     b_fc, y, stats);
  hipLaunchKernelGGL(bn_kernel, dim3(2048), dim3(256), 0, stream, y, x, stats,
                     gamma, beta, (float*)d_out);
}

// Round 2
// 379.946 us; speedup vs baseline: 9.2638x; 9.2638x over previous
//
#include <hip/hip_runtime.h>
#include <hip/hip_bf16.h>
#include <math.h>

#define BN 2
#define NPTS 4096
#define DIM 64
#define HID 256
#define KNB 16

// ---------------------------------------------------------------------------
// Kernel 1: qkv = x @ w_qkv + b_qkv.   [8192,64] @ [64,192]
// ---------------------------------------------------------------------------
__global__ __launch_bounds__(256) void qkv_kernel(
    const float* __restrict__ x, const float* __restrict__ w,
    const float* __restrict__ b, float* __restrict__ qkv) {
  __shared__ float sw[64 * 192];   // 48 KB
  __shared__ float sx[32 * 64];    // 8 KB
  int tid = threadIdx.x;
  int row0 = blockIdx.x * 32;
  for (int o = tid; o < 64 * 192; o += 256) sw[o] = w[o];
  for (int o = tid; o < 32 * 64; o += 256) sx[o] = x[(size_t)row0 * 64 + o];
  __syncthreads();
  for (int o = tid; o < 32 * 192; o += 256) {
    int r = o / 192, c = o % 192;
    float acc = b[c];
    const float* xr = &sx[r * 64];
#pragma unroll
    for (int d = 0; d < 64; ++d) acc = fmaf(xr[d], sw[d * 192 + c], acc);
    qkv[(size_t)(row0 + r) * 192 + c] = acc;
  }
}

// ---------------------------------------------------------------------------
// Kernel 2 (v2): KNN top-16 via histogram select. One block per point.
//   Phase 1: all 4096 dists -> LDS + 2048-bin histogram of float bits>>21.
//   Phase 2: scan histogram for threshold bin T (16th smallest lives in T).
//   Phase 3: compact-collect candidates with bin <= T (expected ~20).
//   Phase 4: exact rank selection with reference (dist, idx) tie-break.
// ---------------------------------------------------------------------------
__global__ __launch_bounds__(256) void knn_kernel(
    const float* __restrict__ pos, int* __restrict__ knn) {
  __shared__ float sdist[NPTS];        // 16 KB
  __shared__ unsigned int hist[2048];  // 8 KB
  __shared__ float ld[256];            // 1 KB
  __shared__ int lidx[256];            // 1 KB
  __shared__ unsigned int wavesum[4];
  __shared__ unsigned int scnt;
  __shared__ int sT;

  int bi = blockIdx.x;          // b*4096 + i
  int b = bi >> 12;
  int i = bi & (NPTS - 1);
  int tid = threadIdx.x;
  int lane = tid & 63, wv = tid >> 6;
  const float* posb = pos + (size_t)b * NPTS * 3;

#pragma unroll
  for (int h = 0; h < 8; ++h) hist[h * 256 + tid] = 0;
  if (tid == 0) { scnt = 0; sT = 2047; }
  float pix = posb[i * 3 + 0], piy = posb[i * 3 + 1], piz = posb[i * 3 + 2];
  __syncthreads();

  // Phase 1: distances + histogram
  for (int c = 0; c < NPTS / 256; ++c) {
    int j = c * 256 + tid;
    float dx = pix - posb[j * 3 + 0];
    float dy = piy - posb[j * 3 + 1];
    float dz = piz - posb[j * 3 + 2];
    float d = sqrtf(dx * dx + dy * dy + dz * dz);
    sdist[j] = d;
    unsigned int bin = __float_as_uint(d) >> 21;   // always < 2048 for d>=0
    atomicAdd(&hist[bin], 1u);
  }
  __syncthreads();

  // Phase 2: find threshold bin T = smallest bin with cum(<=T) >= 16.
  unsigned int s = 0;
#pragma unroll
  for (int h = 0; h < 8; ++h) s += hist[tid * 8 + h];
  unsigned int sOrig = s;
  // wave inclusive scan
#pragma unroll
  for (int off = 1; off < 64; off <<= 1) {
    unsigned int v = __shfl_up(s, off);
    if (lane >= off) s += v;
  }
  if (lane == 63) wavesum[wv] = s;
  __syncthreads();
  unsigned int cum = s;
  for (int ww = 0; ww < wv; ++ww) cum += wavesum[ww];
  unsigned int prev = cum - sOrig;
  if (prev < KNB && cum >= KNB) {
    unsigned int c = prev;
#pragma unroll
    for (int h = 0; h < 8; ++h) {
      c += hist[tid * 8 + h];
      if (c >= KNB) { sT = tid * 8 + h; break; }
    }
  }
  __syncthreads();
  int T = sT;

  // Phase 3: collect candidates with bin <= T
  for (int c = 0; c < NPTS / 256; ++c) {
    int j = c * 256 + tid;
    float d = sdist[j];
    int bin = (int)(__float_as_uint(d) >> 21);
    if (bin <= T) {
      unsigned int p = atomicAdd(&scnt, 1u);
      if (p < 256) { ld[p] = d; lidx[p] = j; }
    }
  }
  __syncthreads();

  // Phase 4: rank selection (exact reference tie-break: dist asc, idx asc)
  int L = (int)scnt;
  if (L > 256) L = 256;
  if (tid < L) {
    float di = ld[tid];
    int ji = lidx[tid];
    int rank = 0;
    for (int m = 0; m < L; ++m) {
      float dm = ld[m];
      int jm = lidx[m];
      rank += (dm < di) || (dm == di && jm < ji);
    }
    if (rank < KNB) knn[(size_t)bi * KNB + rank] = ji;
  }
}

// ---------------------------------------------------------------------------
// Kernel 3: per-point attention. One block (256 thr) per (b,i).
// ---------------------------------------------------------------------------
__global__ __launch_bounds__(256) void attn_kernel(
    const float* __restrict__ qkv, const float* __restrict__ pos,
    const int* __restrict__ knn,
    const float* __restrict__ w_p1, const float* __restrict__ b_p1,
    const float* __restrict__ w_p2, const float* __restrict__ b_p2,
    const float* __restrict__ w_a1, const float* __restrict__ b_a1,
    const float* __restrict__ w_a2, const float* __restrict__ b_a2,
    float* __restrict__ aggout) {
  __shared__ int sidx[16];
  __shared__ float sq[64];
  __shared__ float spi[3];
  __shared__ float se[16][64];          // 4 KB
  __shared__ float sh[16][64];          // 4 KB
  __shared__ float sv[16][64];          // 4 KB
  __shared__ float st[16][256];         // 16 KB
  __shared__ float ssc[16][64];         // 4 KB
  __shared__ float spart[4][16][64];    // 16 KB

  int bi = blockIdx.x;            // b*4096 + i
  int b = bi >> 12;
  int tid = threadIdx.x;
  if (tid < 16) sidx[tid] = knn[(size_t)bi * KNB + tid];
  if (tid < 64) sq[tid] = qkv[(size_t)bi * 192 + tid];
  if (tid < 3) spi[tid] = pos[(size_t)bi * 3 + tid];
  __syncthreads();

  // e[k][p]
  for (int o = tid; o < 16 * 64; o += 256) {
    int k = o >> 6, p = o & 63;
    int jb = (b << 12) | sidx[k];
    float rx = spi[0] - pos[(size_t)jb * 3 + 0];
    float ry = spi[1] - pos[(size_t)jb * 3 + 1];
    float rz = spi[2] - pos[(size_t)jb * 3 + 2];
    float acc = b_p1[p];
    acc = fmaf(rx, w_p1[p], acc);
    acc = fmaf(ry, w_p1[64 + p], acc);
    acc = fmaf(rz, w_p1[128 + p], acc);
    se[k][p] = fmaxf(acc, 0.f);
  }
  __syncthreads();

  // h[k][d] and v_nb[k][d]
  for (int o = tid; o < 16 * 64; o += 256) {
    int k = o >> 6, d = o & 63;
    int jb = (b << 12) | sidx[k];
    float acc = b_p2[d];
#pragma unroll
    for (int p = 0; p < 64; ++p) acc = fmaf(se[k][p], w_p2[p * 64 + d], acc);
    float kv = qkv[(size_t)jb * 192 + 64 + d];
    sh[k][d] = sq[d] - kv + acc;
    sv[k][d] = qkv[(size_t)jb * 192 + 128 + d];
  }
  __syncthreads();

  // t[k][j]: thread owns column j = tid, 16 k-accumulators in regs.
  {
    int j = tid;
    float acc[16];
#pragma unroll
    for (int k = 0; k < 16; ++k) acc[k] = b_a1[j];
    for (int d = 0; d < 64; ++d) {
      float wvv = w_a1[d * 256 + j];
#pragma unroll
      for (int k = 0; k < 16; ++k) acc[k] = fmaf(sh[k][d], wvv, acc[k]);
    }
#pragma unroll
    for (int k = 0; k < 16; ++k) st[k][j] = fmaxf(acc[k], 0.f);
  }
  __syncthreads();

  // sc[k][d]: wave w handles j in [w*64,(w+1)*64); partials reduced in LDS.
  {
    int lane = tid & 63, w = tid >> 6;
    float acc[16];
#pragma unroll
    for (int k = 0; k < 16; ++k) acc[k] = 0.f;
    for (int jj = 0; jj < 64; ++jj) {
      int j = w * 64 + jj;
      float wvv = w_a2[j * 64 + lane];
#pragma unroll
      for (int k = 0; k < 16; ++k) acc[k] = fmaf(st[k][j], wvv, acc[k]);
    }
#pragma unroll
    for (int k = 0; k < 16; ++k) spart[w][k][lane] = acc[k];
  }
  __syncthreads();
  for (int o = tid; o < 16 * 64; o += 256) {
    int k = o >> 6, d = o & 63;
    ssc[k][d] = b_a2[d] + spart[0][k][d] + spart[1][k][d] + spart[2][k][d] +
                spart[3][k][d];
  }
  __syncthreads();

  // softmax over k (per channel d) + weighted sum of v
  if (tid < 64) {
    int d = tid;
    float m = -1e30f;
#pragma unroll
    for (int k = 0; k < 16; ++k) m = fmaxf(m, ssc[k][d]);
    float s = 0.f, a = 0.f;
#pragma unroll
    for (int k = 0; k < 16; ++k) {
      float e = expf(ssc[k][d] - m);
      s += e;
      a = fmaf(e, sv[k][d], a);
    }
    aggout[(size_t)bi * 64 + d] = a / s;
  }
}

// ---------------------------------------------------------------------------
// Kernel 4: y = agg @ w_fc + b_fc; accumulate per-channel sum/sumsq.
// ---------------------------------------------------------------------------
__global__ __launch_bounds__(256) void fc_kernel(
    const float* __restrict__ agg, const float* __restrict__ w_fc,
    const float* __restrict__ b_fc, float* __restrict__ y,
    float* __restrict__ stats) {
  __shared__ float sw[64 * 64];    // 16 KB
  __shared__ float sa[64 * 64];    // 16 KB
  __shared__ float red[4][64];
  __shared__ float red2[4][64];
  int tid = threadIdx.x;
  int r0 = blockIdx.x * 64;
  for (int o = tid; o < 4096; o += 256) sw[o] = w_fc[o];
  for (int o = tid; o < 4096; o += 256) sa[o] = agg[(size_t)r0 * 64 + o];
  __syncthreads();
  int c = tid & 63, g = tid >> 6;
  float psum = 0.f, psq = 0.f;
  for (int rr = g; rr < 64; rr += 4) {
    float acc = b_fc[c];
#pragma unroll
    for (int d = 0; d < 64; ++d) acc = fmaf(sa[rr * 64 + d], sw[d * 64 + c], acc);
    y[(size_t)(r0 + rr) * 64 + c] = acc;
    psum += acc;
    psq = fmaf(acc, acc, psq);
  }
  red[g][c] = psum;
  red2[g][c] = psq;
  __syncthreads();
  if (tid < 64) {
    float s = red[0][tid] + red[1][tid] + red[2][tid] + red[3][tid];
    float s2 = red2[0][tid] + red2[1][tid] + red2[2][tid] + red2[3][tid];
    atomicAdd(&stats[tid], s);
    atomicAdd(&stats[64 + tid], s2);
  }
}

// ---------------------------------------------------------------------------
// Kernel 5: BN (batch stats) + relu + residual.
// ---------------------------------------------------------------------------
__global__ __launch_bounds__(256) void bn_kernel(
    const float* __restrict__ y, const float* __restrict__ x,
    const float* __restrict__ stats, const float* __restrict__ gamma,
    const float* __restrict__ beta, float* __restrict__ out) {
  size_t o = (size_t)blockIdx.x * 256 + threadIdx.x;
  int c = (int)(o & 63);
  const float inv_n = 1.f / 8192.f;
  float mean = stats[c] * inv_n;
  float var = stats[64 + c] * inv_n - mean * mean;
  float inv = rsqrtf(var + 1e-5f);
  float v = (y[o] - mean) * inv * gamma[c] + beta[c];
  out[o] = fmaxf(v, 0.f) + x[o];
}

// ---------------------------------------------------------------------------
extern "C" void kernel_launch(void* const* d_in, const int* in_sizes, int n_in,
                              void* d_out, int out_size, void* d_ws,
                              size_t ws_size, hipStream_t stream) {
  const float* x = (const float*)d_in[0];
  const float* pos = (const float*)d_in[1];
  const float* w_qkv = (const float*)d_in[2];
  const float* b_qkv = (const float*)d_in[3];
  const float* w_p1 = (const float*)d_in[4];
  const float* b_p1 = (const float*)d_in[5];
  const float* w_p2 = (const float*)d_in[6];
  const float* b_p2 = (const float*)d_in[7];
  const float* w_a1 = (const float*)d_in[8];
  const float* b_a1 = (const float*)d_in[9];
  const float* w_a2 = (const float*)d_in[10];
  const float* b_a2 = (const float*)d_in[11];
  const float* w_fc = (const float*)d_in[12];
  const float* b_fc = (const float*)d_in[13];
  const float* gamma = (const float*)d_in[14];
  const float* beta = (const float*)d_in[15];

  char* ws = (char*)d_ws;
  float* qkv = (float*)(ws + 0);              // 8192*192*4 = 6291456
  int* knn = (int*)(ws + 6291456);            // 8192*16*4  = 524288
  float* agg = (float*)(ws + 6815744);        // 8192*64*4  = 2097152
  float* y = (float*)(ws + 8912896);          // 8192*64*4  = 2097152
  float* stats = (float*)(ws + 11010048);     // 128*4      = 512

  hipMemsetAsync(stats, 0, 512, stream);
  hipLaunchKernelGGL(qkv_kernel, dim3(256), dim3(256), 0, stream, x, w_qkv,
                     b_qkv, qkv);
  hipLaunchKernelGGL(knn_kernel, dim3(8192), dim3(256), 0, stream, pos, knn);
  hipLaunchKernelGGL(attn_kernel, dim3(8192), dim3(256), 0, stream, qkv, pos,
                     knn, w_p1, b_p1, w_p2, b_p2, w_a1, b_a1, w_a2, b_a2, agg);
  hipLaunchKernelGGL(fc_kernel, dim3(128), dim3(256), 0, stream, agg, w_fc,
                     b_fc, y, stats);
  hipLaunchKernelGGL(bn_kernel, dim3(2048), dim3(256), 0, stream, y, x, stats,
                     gamma, beta, (float*)d_out);
}

// Round 3
// 224.840 us; speedup vs baseline: 15.6544x; 1.6899x over previous
//
#include <hip/hip_runtime.h>
#include <hip/hip_bf16.h>
#include <math.h>

#define BN 2
#define NPTS 4096
#define DIM 64
#define HID 256
#define KNB 16

typedef __attribute__((ext_vector_type(8))) short bf16x8;
typedef __attribute__((ext_vector_type(4))) float f32x4;
#define MFMA16(a, b, c) __builtin_amdgcn_mfma_f32_16x16x32_bf16(a, b, c, 0, 0, 0)

__device__ __forceinline__ unsigned short f2bf(float f) {
  unsigned int u = __float_as_uint(f);
  unsigned int r = (u + 0x7fffu + ((u >> 16) & 1u)) >> 16;
  return (unsigned short)r;
}

// ---------------------------------------------------------------------------
// Kernel 0: pack w_a1/w_a2/w_p2 to bf16 in MFMA B-fragment lane order.
// frag element: pk[((nt*KS + ks)*64 + lane)*8 + j] = W[ks*32+(lane>>4)*8+j][nt*16+(lane&15)]
// ---------------------------------------------------------------------------
__global__ __launch_bounds__(256) void pack_kernel(
    const float* __restrict__ w_a1, const float* __restrict__ w_a2,
    const float* __restrict__ w_p2, unsigned short* __restrict__ pk1,
    unsigned short* __restrict__ pk2, unsigned short* __restrict__ pkp) {
  int e = blockIdx.x * 256 + threadIdx.x;
  if (e < 16384) {  // w_a1 [64][256]: KS=2, NT=16
    int j = e & 7, lane = (e >> 3) & 63, t = e >> 9;
    int ks = t & 1, nt = t >> 1;
    int k = ks * 32 + ((lane >> 4) << 3) + j, n = nt * 16 + (lane & 15);
    pk1[e] = f2bf(w_a1[k * 256 + n]);
  } else if (e < 32768) {  // w_a2 [256][64]: KS=8, NT=4
    int e2 = e - 16384;
    int j = e2 & 7, lane = (e2 >> 3) & 63, t = e2 >> 9;
    int ks = t & 7, nt = t >> 3;
    int k = ks * 32 + ((lane >> 4) << 3) + j, n = nt * 16 + (lane & 15);
    pk2[e2] = f2bf(w_a2[k * 64 + n]);
  } else if (e < 36864) {  // w_p2 [64][64]: KS=2, NT=4
    int e3 = e - 32768;
    int j = e3 & 7, lane = (e3 >> 3) & 63, t = e3 >> 9;
    int ks = t & 1, nt = t >> 1;
    int k = ks * 32 + ((lane >> 4) << 3) + j, n = nt * 16 + (lane & 15);
    pkp[e3] = f2bf(w_p2[k * 64 + n]);
  }
}

// ---------------------------------------------------------------------------
// Kernel 1: qkv = x @ w_qkv + b_qkv.   [8192,64] @ [64,192]
// ---------------------------------------------------------------------------
__global__ __launch_bounds__(256) void qkv_kernel(
    const float* __restrict__ x, const float* __restrict__ w,
    const float* __restrict__ b, float* __restrict__ qkv) {
  __shared__ float sw[64 * 192];   // 48 KB
  __shared__ float sx[32 * 64];    // 8 KB
  int tid = threadIdx.x;
  int row0 = blockIdx.x * 32;
  for (int o = tid; o < 64 * 192; o += 256) sw[o] = w[o];
  for (int o = tid; o < 32 * 64; o += 256) sx[o] = x[(size_t)row0 * 64 + o];
  __syncthreads();
  for (int o = tid; o < 32 * 192; o += 256) {
    int r = o / 192, c = o % 192;
    float acc = b[c];
    const float* xr = &sx[r * 64];
#pragma unroll
    for (int d = 0; d < 64; ++d) acc = fmaf(xr[d], sw[d * 192 + c], acc);
    qkv[(size_t)(row0 + r) * 192 + c] = acc;
  }
}

// ---------------------------------------------------------------------------
// Kernel 2: KNN top-16 via histogram select (unchanged from R2).
// ---------------------------------------------------------------------------
__global__ __launch_bounds__(256) void knn_kernel(
    const float* __restrict__ pos, int* __restrict__ knn) {
  __shared__ float sdist[NPTS];        // 16 KB
  __shared__ unsigned int hist[2048];  // 8 KB
  __shared__ float ld[256];
  __shared__ int lidx[256];
  __shared__ unsigned int wavesum[4];
  __shared__ unsigned int scnt;
  __shared__ int sT;

  int bi = blockIdx.x;
  int b = bi >> 12;
  int i = bi & (NPTS - 1);
  int tid = threadIdx.x;
  int lane = tid & 63, wv = tid >> 6;
  const float* posb = pos + (size_t)b * NPTS * 3;

#pragma unroll
  for (int h = 0; h < 8; ++h) hist[h * 256 + tid] = 0;
  if (tid == 0) { scnt = 0; sT = 2047; }
  float pix = posb[i * 3 + 0], piy = posb[i * 3 + 1], piz = posb[i * 3 + 2];
  __syncthreads();

  for (int c = 0; c < NPTS / 256; ++c) {
    int j = c * 256 + tid;
    float dx = pix - posb[j * 3 + 0];
    float dy = piy - posb[j * 3 + 1];
    float dz = piz - posb[j * 3 + 2];
    float d = sqrtf(dx * dx + dy * dy + dz * dz);
    sdist[j] = d;
    unsigned int bin = __float_as_uint(d) >> 21;
    atomicAdd(&hist[bin], 1u);
  }
  __syncthreads();

  unsigned int s = 0;
#pragma unroll
  for (int h = 0; h < 8; ++h) s += hist[tid * 8 + h];
  unsigned int sOrig = s;
#pragma unroll
  for (int off = 1; off < 64; off <<= 1) {
    unsigned int v = __shfl_up(s, off);
    if (lane >= off) s += v;
  }
  if (lane == 63) wavesum[wv] = s;
  __syncthreads();
  unsigned int cum = s;
  for (int ww = 0; ww < wv; ++ww) cum += wavesum[ww];
  unsigned int prev = cum - sOrig;
  if (prev < KNB && cum >= KNB) {
    unsigned int c = prev;
#pragma unroll
    for (int h = 0; h < 8; ++h) {
      c += hist[tid * 8 + h];
      if (c >= KNB) { sT = tid * 8 + h; break; }
    }
  }
  __syncthreads();
  int T = sT;

  for (int c = 0; c < NPTS / 256; ++c) {
    int j = c * 256 + tid;
    float d = sdist[j];
    int bin = (int)(__float_as_uint(d) >> 21);
    if (bin <= T) {
      unsigned int p = atomicAdd(&scnt, 1u);
      if (p < 256) { ld[p] = d; lidx[p] = j; }
    }
  }
  __syncthreads();

  int L = (int)scnt;
  if (L > 256) L = 256;
  if (tid < L) {
    float di = ld[tid];
    int ji = lidx[tid];
    int rank = 0;
    for (int m = 0; m < L; ++m) {
      float dm = ld[m];
      int jm = lidx[m];
      rank += (dm < di) || (dm == di && jm < ji);
    }
    if (rank < KNB) knn[(size_t)bi * KNB + rank] = ji;
  }
}

// ---------------------------------------------------------------------------
// Kernel 3 (v2): MFMA attention. One block = 4 points = 64 (p,k) rows.
// Wave w owns point w (16 rows = one 16-row M-tile).
//   phase1: gather q-k, v (fp32->LDS)
//   phase2: e = relu(rel@w_p1+b_p1) (VALU, K=3) -> bf16 LDS
//   phase3: pe = e@w_p2 (MFMA); h = (q-k) + pe + b_p2 -> bf16 LDS
//   phase4: t = relu(h@w_a1+b_a1) (MFMA) -> bf16 LDS
//   phase5: sc = t@w_a2+b_a2 (MFMA) -> fp32 LDS
//   phase6: softmax over k, agg = sum attn*v
// LDS region (33792 B) aliased: {s_qk fp32[64][66], s_e bf16[64][72]} ->
//   s_t bf16[64][264] -> s_sc fp32[64][66].  Strides padded for <=2-way banks.
// ---------------------------------------------------------------------------
__global__ __launch_bounds__(256) void attn_kernel(
    const float* __restrict__ qkv, const float* __restrict__ pos,
    const int* __restrict__ knn, const unsigned short* __restrict__ pk1,
    const unsigned short* __restrict__ pk2,
    const unsigned short* __restrict__ pkp, const float* __restrict__ w_p1,
    const float* __restrict__ b_p1, const float* __restrict__ b_p2,
    const float* __restrict__ b_a1, const float* __restrict__ b_a2,
    float* __restrict__ aggout) {
  __shared__ __align__(16) char region[33792];
  __shared__ __align__(16) unsigned short s_h[64][72];  // 9216 B
  __shared__ float s_v[64][64];                         // 16384 B
  __shared__ int s_idx[64];

  float(*s_qk)[66] = (float(*)[66])region;                          // 16896 B
  unsigned short(*s_e)[72] = (unsigned short(*)[72])(region + 16896);  // 9216 B
  unsigned short(*s_t)[264] = (unsigned short(*)[264])region;       // 33792 B
  float(*s_sc)[66] = (float(*)[66])region;                          // 16896 B

  int tid = threadIdx.x, w = tid >> 6, lane = tid & 63;
  int g0 = blockIdx.x * 4;          // first global point (b*4096+i)
  int b = g0 >> 12;

  if (tid < 64) {
    int p = tid >> 4, k = tid & 15;
    s_idx[tid] = knn[(size_t)(g0 + p) * KNB + k];
  }
  __syncthreads();

  // phase 1: gather  (row r = p*16+k; wave w does rows r%4==w)
  for (int it = 0; it < 16; ++it) {
    int r = it * 4 + w;
    int g = g0 + (r >> 4);
    int jb = (b << 12) | s_idx[r];
    float qv = qkv[(size_t)g * 192 + lane];
    float kv = qkv[(size_t)jb * 192 + 64 + lane];
    float vv = qkv[(size_t)jb * 192 + 128 + lane];
    s_qk[r][lane] = qv - kv;
    s_v[r][lane] = vv;
  }
  // phase 2: e (pos-MLP layer 1)
  {
    float w0 = w_p1[lane], w1 = w_p1[64 + lane], w2 = w_p1[128 + lane];
    float bp = b_p1[lane];
    for (int it = 0; it < 16; ++it) {
      int r = it * 4 + w;
      int g = g0 + (r >> 4);
      int jb = (b << 12) | s_idx[r];
      float rx = pos[(size_t)g * 3 + 0] - pos[(size_t)jb * 3 + 0];
      float ry = pos[(size_t)g * 3 + 1] - pos[(size_t)jb * 3 + 1];
      float rz = pos[(size_t)g * 3 + 2] - pos[(size_t)jb * 3 + 2];
      float e = fmaf(rz, w2, fmaf(ry, w1, fmaf(rx, w0, bp)));
      s_e[r][lane] = f2bf(fmaxf(e, 0.f));
    }
  }
  __syncthreads();

  int m = lane & 15, quad = lane >> 4;
  // phase 3: pe GEMM [16,64]@[64,64] per wave + h epilogue
  {
    bf16x8 a0 = *(const bf16x8*)&s_e[16 * w + m][quad * 8];
    bf16x8 a1 = *(const bf16x8*)&s_e[16 * w + m][32 + quad * 8];
#pragma unroll
    for (int nt = 0; nt < 4; ++nt) {
      bf16x8 b0 = *(const bf16x8*)(pkp + ((size_t)(nt * 2 + 0) * 64 + lane) * 8);
      bf16x8 b1 = *(const bf16x8*)(pkp + ((size_t)(nt * 2 + 1) * 64 + lane) * 8);
      f32x4 acc = {0.f, 0.f, 0.f, 0.f};
      acc = MFMA16(a0, b0, acc);
      acc = MFMA16(a1, b1, acc);
      int col = nt * 16 + m;
      float bp2 = b_p2[col];
#pragma unroll
      for (int i = 0; i < 4; ++i) {
        int row = 16 * w + quad * 4 + i;
        float h = s_qk[row][col] + acc[i] + bp2;
        s_h[row][col] = f2bf(h);
      }
    }
  }
  __syncthreads();  // region reuse: s_qk/s_e dead -> s_t live

  // phase 4: GEMM1 [16,64]@[64,256] per wave, relu -> s_t bf16
  {
    bf16x8 a0 = *(const bf16x8*)&s_h[16 * w + m][quad * 8];
    bf16x8 a1 = *(const bf16x8*)&s_h[16 * w + m][32 + quad * 8];
#pragma unroll 4
    for (int nt = 0; nt < 16; ++nt) {
      bf16x8 b0 = *(const bf16x8*)(pk1 + ((size_t)(nt * 2 + 0) * 64 + lane) * 8);
      bf16x8 b1 = *(const bf16x8*)(pk1 + ((size_t)(nt * 2 + 1) * 64 + lane) * 8);
      f32x4 acc = {0.f, 0.f, 0.f, 0.f};
      acc = MFMA16(a0, b0, acc);
      acc = MFMA16(a1, b1, acc);
      int col = nt * 16 + m;
      float ba = b_a1[col];
#pragma unroll
      for (int i = 0; i < 4; ++i) {
        int row = 16 * w + quad * 4 + i;
        s_t[row][col] = f2bf(fmaxf(acc[i] + ba, 0.f));
      }
    }
  }
  // wave-local s_t rows: no barrier needed before phase 5 reads.

  // phase 5: GEMM2 [16,256]@[256,64] per wave
  f32x4 acc2[4];
#pragma unroll
  for (int nt = 0; nt < 4; ++nt) acc2[nt] = (f32x4){0.f, 0.f, 0.f, 0.f};
#pragma unroll
  for (int ks = 0; ks < 8; ++ks) {
    bf16x8 a = *(const bf16x8*)&s_t[16 * w + m][ks * 32 + quad * 8];
#pragma unroll
    for (int nt = 0; nt < 4; ++nt) {
      bf16x8 bb = *(const bf16x8*)(pk2 + ((size_t)(nt * 8 + ks) * 64 + lane) * 8);
      acc2[nt] = MFMA16(a, bb, acc2[nt]);
    }
  }
  __syncthreads();  // all waves done reading s_t before s_sc overwrites region
#pragma unroll
  for (int nt = 0; nt < 4; ++nt) {
    int col = nt * 16 + m;
    float ba2 = b_a2[col];
#pragma unroll
    for (int i = 0; i < 4; ++i)
      s_sc[16 * w + quad * 4 + i][col] = acc2[nt][i] + ba2;
  }
  __syncthreads();

  // phase 6: softmax over k + weighted v sum. thread = (p=w, d=lane)
  {
    int p = w, d = lane;
    float mx = -1e30f;
#pragma unroll
    for (int k = 0; k < 16; ++k) mx = fmaxf(mx, s_sc[p * 16 + k][d]);
    float s = 0.f, a = 0.f;
#pragma unroll
    for (int k = 0; k < 16; ++k) {
      float e = expf(s_sc[p * 16 + k][d] - mx);
      s += e;
      a = fmaf(e, s_v[p * 16 + k][d], a);
    }
    aggout[(size_t)(g0 + p) * 64 + d] = a / s;
  }
}

// ---------------------------------------------------------------------------
// Kernel 4: y = agg @ w_fc + b_fc; accumulate per-channel sum/sumsq.
// ---------------------------------------------------------------------------
__global__ __launch_bounds__(256) void fc_kernel(
    const float* __restrict__ agg, const float* __restrict__ w_fc,
    const float* __restrict__ b_fc, float* __restrict__ y,
    float* __restrict__ stats) {
  __shared__ float sw[64 * 64];
  __shared__ float sa[64 * 64];
  __shared__ float red[4][64];
  __shared__ float red2[4][64];
  int tid = threadIdx.x;
  int r0 = blockIdx.x * 64;
  for (int o = tid; o < 4096; o += 256) sw[o] = w_fc[o];
  for (int o = tid; o < 4096; o += 256) sa[o] = agg[(size_t)r0 * 64 + o];
  __syncthreads();
  int c = tid & 63, g = tid >> 6;
  float psum = 0.f, psq = 0.f;
  for (int rr = g; rr < 64; rr += 4) {
    float acc = b_fc[c];
#pragma unroll
    for (int d = 0; d < 64; ++d) acc = fmaf(sa[rr * 64 + d], sw[d * 64 + c], acc);
    y[(size_t)(r0 + rr) * 64 + c] = acc;
    psum += acc;
    psq = fmaf(acc, acc, psq);
  }
  red[g][c] = psum;
  red2[g][c] = psq;
  __syncthreads();
  if (tid < 64) {
    float s = red[0][tid] + red[1][tid] + red[2][tid] + red[3][tid];
    float s2 = red2[0][tid] + red2[1][tid] + red2[2][tid] + red2[3][tid];
    atomicAdd(&stats[tid], s);
    atomicAdd(&stats[64 + tid], s2);
  }
}

// ---------------------------------------------------------------------------
// Kernel 5: BN (batch stats) + relu + residual.
// ---------------------------------------------------------------------------
__global__ __launch_bounds__(256) void bn_kernel(
    const float* __restrict__ y, const float* __restrict__ x,
    const float* __restrict__ stats, const float* __restrict__ gamma,
    const float* __restrict__ beta, float* __restrict__ out) {
  size_t o = (size_t)blockIdx.x * 256 + threadIdx.x;
  int c = (int)(o & 63);
  const float inv_n = 1.f / 8192.f;
  float mean = stats[c] * inv_n;
  float var = stats[64 + c] * inv_n - mean * mean;
  float inv = rsqrtf(var + 1e-5f);
  float v = (y[o] - mean) * inv * gamma[c] + beta[c];
  out[o] = fmaxf(v, 0.f) + x[o];
}

// ---------------------------------------------------------------------------
extern "C" void kernel_launch(void* const* d_in, const int* in_sizes, int n_in,
                              void* d_out, int out_size, void* d_ws,
                              size_t ws_size, hipStream_t stream) {
  const float* x = (const float*)d_in[0];
  const float* pos = (const float*)d_in[1];
  const float* w_qkv = (const float*)d_in[2];
  const float* b_qkv = (const float*)d_in[3];
  const float* w_p1 = (const float*)d_in[4];
  const float* b_p1 = (const float*)d_in[5];
  const float* w_p2 = (const float*)d_in[6];
  const float* b_p2 = (const float*)d_in[7];
  const float* w_a1 = (const float*)d_in[8];
  const float* b_a1 = (const float*)d_in[9];
  const float* w_a2 = (const float*)d_in[10];
  const float* b_a2 = (const float*)d_in[11];
  const float* w_fc = (const float*)d_in[12];
  const float* b_fc = (const float*)d_in[13];
  const float* gamma = (const float*)d_in[14];
  const float* beta = (const float*)d_in[15];

  char* ws = (char*)d_ws;
  float* qkv = (float*)(ws + 0);                        // 6291456 B
  int* knn = (int*)(ws + 6291456);                      // 524288 B
  float* agg = (float*)(ws + 6815744);                  // 2097152 B
  float* y = (float*)(ws + 8912896);                    // 2097152 B
  float* stats = (float*)(ws + 11010048);               // 512 B
  unsigned short* pk1 = (unsigned short*)(ws + 11010560);  // 32768 B
  unsigned short* pk2 = (unsigned short*)(ws + 11043328);  // 32768 B
  unsigned short* pkp = (unsigned short*)(ws + 11076096);  // 8192 B

  hipMemsetAsync(stats, 0, 512, stream);
  hipLaunchKernelGGL(pack_kernel, dim3(144), dim3(256), 0, stream, w_a1, w_a2,
                     w_p2, pk1, pk2, pkp);
  hipLaunchKernelGGL(qkv_kernel, dim3(256), dim3(256), 0, stream, x, w_qkv,
                     b_qkv, qkv);
  hipLaunchKernelGGL(knn_kernel, dim3(8192), dim3(256), 0, stream, pos, knn);
  hipLaunchKernelGGL(attn_kernel, dim3(2048), dim3(256), 0, stream, qkv, pos,
                     knn, pk1, pk2, pkp, w_p1, b_p1, b_p2, b_a1, b_a2, agg);
  hipLaunchKernelGGL(fc_kernel, dim3(128), dim3(256), 0, stream, agg, w_fc,
                     b_fc, y, stats);
  hipLaunchKernelGGL(bn_kernel, dim3(2048), dim3(256), 0, stream, y, x, stats,
                     gamma, beta, (float*)d_out);
}